// Round 1
// 372.152 us; speedup vs baseline: 1.0302x; 1.0302x over previous
//
#include <hip/hip_runtime.h>
#include <hip/hip_bf16.h>

// FactorizedDenseAttention, MI355X/gfx950.  ALL I/O FP32.
// S[i,j] = sum_m C[i,m]*B[j,m], C = 32*(a[2m]+a[2m+1]) (rank 32)
//   a = q@Wa^T+ba (64ch), B = q@Wb^T+bb (32ch); P = softmax(S); O = P@v.
// d_out = [O: H*L*64 f32][P: H*L*L f32].
// R13: coalesced P stores. R12 stored P as 128 scattered nontemporal dword
// stores/thread (4-row x 64B segments per wave instr) interleaved in the PV
// loop -> partial-line writes + store-issue overhead; effective write BW
// ~1.7 TB/s. Now P rows are streamed from the ps LDS buffer (already filled
// in bf16 for the PV MFMA): wave w owns rows w*4+quad, reads ds_read_b64,
// converts (<<16) and scales by 1/l, stores global_store_dwordx4 -> 1KB
// contiguous per wave instr, 32 stores/thread. P precision now bf16-p_hat
// (error <= 2^-9, well under the 0.03125 absmax from O). Also split PV
// accumulator o -> o0/o1 to halve the dependent-MFMA chain.
// Barrier count unchanged (5/block).

#define HN 16
#define LN 2048
#define KR 32

typedef __attribute__((ext_vector_type(8))) short bf16x8;
typedef __attribute__((ext_vector_type(4))) float f32x4;

__device__ __forceinline__ float b2f(unsigned short u) {
    return __uint_as_float(((unsigned int)u) << 16);
}
__device__ __forceinline__ unsigned short f2b(float f) {
    __hip_bfloat16 h = __float2bfloat16(f);   // RNE
    return *reinterpret_cast<unsigned short*>(&h);
}

// B-tile per (h, jc): 8KB = 4096 shorts:
//   [0,2048): Bhi [kg=0..3][c=0..63] granules of 8 bf16 (k=kg*8..+8)
//   [2048,4096): Blo same
// V-tile per (h, jc): 8KB = 4096 shorts: [jg=0..7][d=0..63] granules of 8
//   bf16 = bf16(v[h][jc*64+jg*8 .. +8][d])
#define TILE_B 4096
#define TILE_V 4096

// ---------------------------------------------------------------------------
// K1a: thread = (row, kg): 8 m's. Weights in LDS. Chi/Clo row-major (A-frag
// layout), Bhi/Blo in 8KB tile-granule layout.  [validated R8-R12]
// ---------------------------------------------------------------------------
__global__ __launch_bounds__(256) void k_cb(
    const float* __restrict__ q,
    const float* __restrict__ Wa, const float* __restrict__ ba,
    const float* __restrict__ Wb, const float* __restrict__ bb,
    unsigned short* __restrict__ Chi, unsigned short* __restrict__ Clo,
    unsigned short* __restrict__ TileB)
{
    __shared__ float sWa[64 * 64];
    __shared__ float sWb[32 * 64];
    __shared__ float sba[64];
    __shared__ float sbb[32];
    const int tid = threadIdx.x;
    for (int i = tid; i < 64 * 64; i += 256) sWa[i] = Wa[i];
    for (int i = tid; i < 32 * 64; i += 256) sWb[i] = Wb[i];
    if (tid < 64) sba[tid] = ba[tid];
    if (tid < 32) sbb[tid] = bb[tid];
    __syncthreads();

    const int t = blockIdx.x * 256 + tid;
    const int row = t >> 2, kg = t & 3, mh = kg * 8;   // m in [mh, mh+8)
    const int h = row >> 11, i = row & 2047;
    const int jc = i >> 6, c = i & 63;

    float qf[64];
    const float4* q4p = reinterpret_cast<const float4*>(q + (size_t)row * 64);
    #pragma unroll
    for (int k4 = 0; k4 < 16; ++k4) {
        float4 u = q4p[k4];
        qf[4*k4+0] = u.x; qf[4*k4+1] = u.y; qf[4*k4+2] = u.z; qf[4*k4+3] = u.w;
    }
    unsigned short chb[8], clb[8], bhb[8], blb[8];
    #pragma unroll
    for (int mi = 0; mi < 8; ++mi) {
        const int m = mh + mi;
        float a0 = sba[2*m], a1 = sba[2*m+1], bv = sbb[m];
        const float4* wa0 = reinterpret_cast<const float4*>(&sWa[(2*m) * 64]);
        const float4* wa1 = reinterpret_cast<const float4*>(&sWa[(2*m+1) * 64]);
        const float4* wb0 = reinterpret_cast<const float4*>(&sWb[m * 64]);
        #pragma unroll
        for (int k4 = 0; k4 < 16; ++k4) {
            float4 w0 = wa0[k4], w1 = wa1[k4], w2 = wb0[k4];
            float x0 = qf[4*k4], x1 = qf[4*k4+1], x2 = qf[4*k4+2], x3 = qf[4*k4+3];
            a0 = fmaf(x0, w0.x, a0); a0 = fmaf(x1, w0.y, a0);
            a0 = fmaf(x2, w0.z, a0); a0 = fmaf(x3, w0.w, a0);
            a1 = fmaf(x0, w1.x, a1); a1 = fmaf(x1, w1.y, a1);
            a1 = fmaf(x2, w1.z, a1); a1 = fmaf(x3, w1.w, a1);
            bv = fmaf(x0, w2.x, bv); bv = fmaf(x1, w2.y, bv);
            bv = fmaf(x2, w2.z, bv); bv = fmaf(x3, w2.w, bv);
        }
        float cc = 32.f * (a0 + a1);                  // fold repeat factor
        unsigned short ch = f2b(cc);
        chb[mi] = ch; clb[mi] = f2b(cc - b2f(ch));
        unsigned short bh = f2b(bv);
        bhb[mi] = bh; blb[mi] = f2b(bv - b2f(bh));
    }
    *reinterpret_cast<uint4*>(Chi + (size_t)row * KR + mh) = *reinterpret_cast<uint4*>(chb);
    *reinterpret_cast<uint4*>(Clo + (size_t)row * KR + mh) = *reinterpret_cast<uint4*>(clb);
    unsigned short* tb = TileB + (size_t)(h * 32 + jc) * TILE_B + (kg * 64 + c) * 8;
    *reinterpret_cast<uint4*>(tb)        = *reinterpret_cast<uint4*>(bhb);
    *reinterpret_cast<uint4*>(tb + 2048) = *reinterpret_cast<uint4*>(blb);
}

// ---------------------------------------------------------------------------
// K1b: V tiles (granule layout) via LDS transpose.  [validated R6-R12]
// ---------------------------------------------------------------------------
__global__ __launch_bounds__(256) void k_vtc(
    const float* __restrict__ v, unsigned short* __restrict__ TileV)
{
    __shared__ unsigned short sv[64 * 66];   // [j][d], stride 66
    const int tid = threadIdx.x;
    const int h = blockIdx.x >> 5, jc = blockIdx.x & 31;
    const float* src = v + (size_t)(h * LN + jc * 64) * 64;
    for (int i = tid; i < 4096; i += 256)
        sv[(i >> 6) * 66 + (i & 63)] = f2b(src[i]);
    __syncthreads();
    unsigned short* vt = TileV + (size_t)(h * 32 + jc) * TILE_V;
    #pragma unroll
    for (int it = 0; it < 2; ++it) {
        const int gi = tid + it * 256;               // 0..511
        const int jg = gi >> 6, d = gi & 63;
        unsigned short g8[8];
        #pragma unroll
        for (int jj = 0; jj < 8; ++jj)
            g8[jj] = sv[(jg * 8 + jj) * 66 + d];
        *reinterpret_cast<uint4*>(vt + (jg * 64 + d) * 8) = *reinterpret_cast<uint4*>(g8);
    }
}

// ---------------------------------------------------------------------------
// K2 (fused, single-S): 16-row blocks, 2048 total.
// Wave w owns col-subtile w (loop1) and d-slice w (PV); S in 128 VGPRs.
// B/V fragments read directly from global (L2-resident granule tiles).
// p_hat exchanged via half-width LDS (16 x 1024 bf16), filled per 16 chunks;
// P rows stored coalesced from that same buffer (wave w owns rows w*4+quad).
// b: [2:0]=xcd, [9:3]=tile(128), [10]=hbit; h=(b&7)*2+(b>>10).
// ---------------------------------------------------------------------------
#define PS_STRIDE 1032
__global__ __launch_bounds__(256, 2) void k_fuse(
    const unsigned short* __restrict__ Chi, const unsigned short* __restrict__ Clo,
    const unsigned short* __restrict__ TileB, const unsigned short* __restrict__ TileV,
    float* __restrict__ outO, float* __restrict__ outP)
{
    __shared__ unsigned short ps[16 * PS_STRIDE];   // 33KB: 16 rows x 1024 cols
    __shared__ float sRedM[4][16];
    __shared__ float sRedL[4][16];

    const int b = blockIdx.x;
    const int h = (b & 7) * 2 + (b >> 10);       // XCD-aware head mapping
    const int tile = (b >> 3) & 127;
    const int tid = threadIdx.x, w = tid >> 6, lane = tid & 63;
    const int quad = lane >> 4, n16 = lane & 15;
    const int rbase = tile * 16;
    const int hL = h * LN;

    const bf16x8 ahi = *reinterpret_cast<const bf16x8*>(Chi + (size_t)(hL + rbase + n16) * KR + quad * 8);
    const bf16x8 alo = *reinterpret_cast<const bf16x8*>(Clo + (size_t)(hL + rbase + n16) * KR + quad * 8);

    const unsigned short* bTile = TileB + (size_t)(h * 32) * TILE_B;
    const unsigned short* vTile = TileV + (size_t)(h * 32) * TILE_V;
    const int fragW = (quad * 64 + w * 16 + n16) * 8;   // B granule, shorts

    f32x4 zero = {0.f, 0.f, 0.f, 0.f};
    f32x4 sS[32];                                 // the S strip (128 VGPRs)

    // ---- loop 1: S -> registers, B-frags direct from global (no barriers) ----
    #pragma unroll
    for (int jc = 0; jc < 32; ++jc) {
        const unsigned short* g = bTile + jc * TILE_B;
        bf16x8 bhi = *reinterpret_cast<const bf16x8*>(g + fragW);
        bf16x8 blo = *reinterpret_cast<const bf16x8*>(g + 2048 + fragW);
        f32x4 acc = zero;
        acc = __builtin_amdgcn_mfma_f32_16x16x32_bf16(ahi, bhi, acc, 0, 0, 0);
        acc = __builtin_amdgcn_mfma_f32_16x16x32_bf16(ahi, blo, acc, 0, 0, 0);
        acc = __builtin_amdgcn_mfma_f32_16x16x32_bf16(alo, bhi, acc, 0, 0, 0);
        sS[jc] = acc;
    }

    // ---- stats in registers: m, then S -> p_hat with l accumulation ----
    float mr[4], li[4], liS;
    const int srow = w * 4 + quad;               // row this thread stores in P
    {
        float m0[4];
        #pragma unroll
        for (int r = 0; r < 4; ++r) {
            float mm = sS[0][r];
            #pragma unroll
            for (int jc = 1; jc < 32; ++jc) mm = fmaxf(mm, sS[jc][r]);
            #pragma unroll
            for (int off = 1; off <= 8; off <<= 1)
                mm = fmaxf(mm, __shfl_xor(mm, off, 64));
            m0[r] = mm;
        }
        if (n16 == 0) {
            #pragma unroll
            for (int r = 0; r < 4; ++r) sRedM[w][quad * 4 + r] = m0[r];
        }
        __syncthreads();
        #pragma unroll
        for (int r = 0; r < 4; ++r)
            mr[r] = fmaxf(fmaxf(sRedM[0][quad*4+r], sRedM[1][quad*4+r]),
                          fmaxf(sRedM[2][quad*4+r], sRedM[3][quad*4+r]));
        float l0[4] = {0.f, 0.f, 0.f, 0.f};
        #pragma unroll
        for (int jc = 0; jc < 32; ++jc) {
            #pragma unroll
            for (int r = 0; r < 4; ++r) {
                float p = __expf(sS[jc][r] - mr[r]);  // <= 1, = 1 at the max
                sS[jc][r] = p;
                l0[r] += p;
            }
        }
        #pragma unroll
        for (int r = 0; r < 4; ++r) {
            float ll = l0[r];
            #pragma unroll
            for (int off = 1; off <= 8; off <<= 1)
                ll += __shfl_xor(ll, off, 64);
            l0[r] = ll;
        }
        if (n16 == 0) {
            #pragma unroll
            for (int r = 0; r < 4; ++r) sRedL[w][quad * 4 + r] = l0[r];
        }
        __syncthreads();
        #pragma unroll
        for (int r = 0; r < 4; ++r)
            li[r] = 1.f / (sRedL[0][quad*4+r] + sRedL[1][quad*4+r]
                         + sRedL[2][quad*4+r] + sRedL[3][quad*4+r]);
        liS = 1.f / (sRedL[0][srow] + sRedL[1][srow]
                   + sRedL[2][srow] + sRedL[3][srow]);
    }

    // ---- loop 2: two 16-chunk halves; per half: fill ps, barrier, then
    //      barrier-free PV (V-frags direct from global) + coalesced P rows ----
    f32x4 o0 = zero, o1 = zero;
    float* prow = outP + (size_t)(hL + rbase + srow) * LN;
    #pragma unroll
    for (int half = 0; half < 2; ++half) {
        if (half) __syncthreads();           // ps reads of half 0 complete
        const int jc0 = half * 16;
        #pragma unroll
        for (int ji = 0; ji < 16; ++ji) {
            #pragma unroll
            for (int r = 0; r < 4; ++r)
                ps[(quad * 4 + r) * PS_STRIDE + ji * 64 + w * 16 + n16]
                    = f2b(sS[jc0 + ji][r]);
        }
        __syncthreads();                     // ps visible to all waves

        // PV: V-frags direct from global, p_hat frags from ps
        #pragma unroll
        for (int ji = 0; ji < 16; ++ji) {
            const int jc = jc0 + ji;
            const unsigned short* vt = vTile + jc * TILE_V;
            bf16x8 pa0 = *reinterpret_cast<const bf16x8*>(
                ps + n16 * PS_STRIDE + ji * 64 + quad * 8);
            bf16x8 pa1 = *reinterpret_cast<const bf16x8*>(
                ps + n16 * PS_STRIDE + ji * 64 + 32 + quad * 8);
            bf16x8 vb0 = *reinterpret_cast<const bf16x8*>(
                vt + (quad * 64 + w * 16 + n16) * 8);
            bf16x8 vb1 = *reinterpret_cast<const bf16x8*>(
                vt + ((4 + quad) * 64 + w * 16 + n16) * 8);
            o0 = __builtin_amdgcn_mfma_f32_16x16x32_bf16(pa0, vb0, o0, 0, 0, 0);
            o1 = __builtin_amdgcn_mfma_f32_16x16x32_bf16(pa1, vb1, o1, 0, 0, 0);
        }

        // P stores: wave w streams rows w*4+quad, 1KB contiguous per instr
        #pragma unroll
        for (int ch = 0; ch < 16; ++ch) {
            const unsigned short* pp = ps + srow * PS_STRIDE + ch * 64 + n16 * 4;
            uint2 u = *reinterpret_cast<const uint2*>(pp);
            f32x4 pv;
            pv[0] = __uint_as_float((u.x & 0xffffu) << 16) * liS;
            pv[1] = __uint_as_float(u.x & 0xffff0000u) * liS;
            pv[2] = __uint_as_float((u.y & 0xffffu) << 16) * liS;
            pv[3] = __uint_as_float(u.y & 0xffff0000u) * liS;
            __builtin_nontemporal_store(pv, reinterpret_cast<f32x4*>(
                prow + half * 1024 + ch * 64 + n16 * 4));
        }
    }
    // O = (sum p_hat * V) * li
    #pragma unroll
    for (int r = 0; r < 4; ++r)
        __builtin_nontemporal_store((o0[r] + o1[r]) * li[r],
            &outO[(size_t)(hL + rbase + quad * 4 + r) * 64 + w * 16 + n16]);
}

// ---------------------------------------------------------------------------
extern "C" void kernel_launch(void* const* d_in, const int* in_sizes, int n_in,
                              void* d_out, int out_size, void* d_ws, size_t ws_size,
                              hipStream_t stream)
{
    (void)in_sizes; (void)n_in; (void)out_size; (void)ws_size;
    const float* q  = (const float*)d_in[0];
    const float* v  = (const float*)d_in[1];
    const float* Wa = (const float*)d_in[2];
    const float* ba = (const float*)d_in[3];
    const float* Wb = (const float*)d_in[4];
    const float* bb = (const float*)d_in[5];

    float* out = (float*)d_out;
    char* wsb = (char*)d_ws;
    const size_t MB = 1024 * 1024;
    unsigned short* Chi   = (unsigned short*)(wsb);            // 2MB
    unsigned short* Clo   = (unsigned short*)(wsb + 2 * MB);   // 2MB
    unsigned short* TileB = (unsigned short*)(wsb + 4 * MB);   // 4MB (512 x 8KB)
    unsigned short* TileV = (unsigned short*)(wsb + 8 * MB);   // 4MB (512 x 8KB)

    float* outO = out;                          // [H*L*64]
    float* outP = out + (size_t)HN * LN * 64;   // [H*L*L]

    hipLaunchKernelGGL(k_cb, dim3(512), dim3(256), 0, stream,
                       q, Wa, ba, Wb, bb, Chi, Clo, TileB);
    hipLaunchKernelGGL(k_vtc, dim3(512), dim3(256), 0, stream, v, TileV);
    hipLaunchKernelGGL(k_fuse, dim3(2048), dim3(256), 0, stream,
                       Chi, Clo, TileB, TileV, outO, outP);
}

// Round 2
// 370.364 us; speedup vs baseline: 1.0352x; 1.0048x over previous
//
#include <hip/hip_runtime.h>
#include <hip/hip_bf16.h>

// FactorizedDenseAttention, MI355X/gfx950.  ALL I/O FP32.
// S[i,j] = sum_m C[i,m]*B[j,m], C = 32*(a[2m]+a[2m+1]) (rank 32)
//   a = q@Wa^T+ba (64ch), B = q@Wb^T+bb (32ch); P = softmax(S); O = P@v.
// d_out = [O: H*L*64 f32][P: H*L*L f32].
// R14: LDS-only barriers. __syncthreads() emits s_waitcnt vmcnt(0)
// lgkmcnt(0) before s_barrier -> each of the 5 barriers/block drained ALL
// in-flight global traffic (loop1 B-loads, PV vb loads, and the 16 NT
// dwordx4 P-stores/thread, which ack from HBM). With 2 phase-aligned
// blocks/CU this made every barrier a GPU-wide pipeline drain, x8 rounds.
// Now: raw s_barrier + s_waitcnt lgkmcnt(0) only (LDS handoffs are the only
// cross-wave dependency), fenced with sched_barrier(0) + "memory" clobber
// per guide rule #18. P-stores/loads stay in flight across barriers.
// Math identical to R13 (coalesced P rows from ps, o0/o1 split).

#define HN 16
#define LN 2048
#define KR 32

typedef __attribute__((ext_vector_type(8))) short bf16x8;
typedef __attribute__((ext_vector_type(4))) float f32x4;

__device__ __forceinline__ float b2f(unsigned short u) {
    return __uint_as_float(((unsigned int)u) << 16);
}
__device__ __forceinline__ unsigned short f2b(float f) {
    __hip_bfloat16 h = __float2bfloat16(f);   // RNE
    return *reinterpret_cast<unsigned short*>(&h);
}

// Barrier that waits ONLY on LDS ops (lgkmcnt), never vmcnt: global
// loads/stores in flight are not drained.  sched_barrier(0) pins ds ops
// on both sides (hipcc hoists past inline-asm waitcnt otherwise, rule #18).
__device__ __forceinline__ void bar_lds() {
    __builtin_amdgcn_sched_barrier(0);
    asm volatile("s_waitcnt lgkmcnt(0)" ::: "memory");
    __builtin_amdgcn_s_barrier();
    __builtin_amdgcn_sched_barrier(0);
}

// B-tile per (h, jc): 8KB = 4096 shorts:
//   [0,2048): Bhi [kg=0..3][c=0..63] granules of 8 bf16 (k=kg*8..+8)
//   [2048,4096): Blo same
// V-tile per (h, jc): 8KB = 4096 shorts: [jg=0..7][d=0..63] granules of 8
//   bf16 = bf16(v[h][jc*64+jg*8 .. +8][d])
#define TILE_B 4096
#define TILE_V 4096

// ---------------------------------------------------------------------------
// K1a: thread = (row, kg): 8 m's. Weights in LDS. Chi/Clo row-major (A-frag
// layout), Bhi/Blo in 8KB tile-granule layout.  [validated R8-R13]
// ---------------------------------------------------------------------------
__global__ __launch_bounds__(256) void k_cb(
    const float* __restrict__ q,
    const float* __restrict__ Wa, const float* __restrict__ ba,
    const float* __restrict__ Wb, const float* __restrict__ bb,
    unsigned short* __restrict__ Chi, unsigned short* __restrict__ Clo,
    unsigned short* __restrict__ TileB)
{
    __shared__ float sWa[64 * 64];
    __shared__ float sWb[32 * 64];
    __shared__ float sba[64];
    __shared__ float sbb[32];
    const int tid = threadIdx.x;
    for (int i = tid; i < 64 * 64; i += 256) sWa[i] = Wa[i];
    for (int i = tid; i < 32 * 64; i += 256) sWb[i] = Wb[i];
    if (tid < 64) sba[tid] = ba[tid];
    if (tid < 32) sbb[tid] = bb[tid];
    __syncthreads();

    const int t = blockIdx.x * 256 + tid;
    const int row = t >> 2, kg = t & 3, mh = kg * 8;   // m in [mh, mh+8)
    const int h = row >> 11, i = row & 2047;
    const int jc = i >> 6, c = i & 63;

    float qf[64];
    const float4* q4p = reinterpret_cast<const float4*>(q + (size_t)row * 64);
    #pragma unroll
    for (int k4 = 0; k4 < 16; ++k4) {
        float4 u = q4p[k4];
        qf[4*k4+0] = u.x; qf[4*k4+1] = u.y; qf[4*k4+2] = u.z; qf[4*k4+3] = u.w;
    }
    unsigned short chb[8], clb[8], bhb[8], blb[8];
    #pragma unroll
    for (int mi = 0; mi < 8; ++mi) {
        const int m = mh + mi;
        float a0 = sba[2*m], a1 = sba[2*m+1], bv = sbb[m];
        const float4* wa0 = reinterpret_cast<const float4*>(&sWa[(2*m) * 64]);
        const float4* wa1 = reinterpret_cast<const float4*>(&sWa[(2*m+1) * 64]);
        const float4* wb0 = reinterpret_cast<const float4*>(&sWb[m * 64]);
        #pragma unroll
        for (int k4 = 0; k4 < 16; ++k4) {
            float4 w0 = wa0[k4], w1 = wa1[k4], w2 = wb0[k4];
            float x0 = qf[4*k4], x1 = qf[4*k4+1], x2 = qf[4*k4+2], x3 = qf[4*k4+3];
            a0 = fmaf(x0, w0.x, a0); a0 = fmaf(x1, w0.y, a0);
            a0 = fmaf(x2, w0.z, a0); a0 = fmaf(x3, w0.w, a0);
            a1 = fmaf(x0, w1.x, a1); a1 = fmaf(x1, w1.y, a1);
            a1 = fmaf(x2, w1.z, a1); a1 = fmaf(x3, w1.w, a1);
            bv = fmaf(x0, w2.x, bv); bv = fmaf(x1, w2.y, bv);
            bv = fmaf(x2, w2.z, bv); bv = fmaf(x3, w2.w, bv);
        }
        float cc = 32.f * (a0 + a1);                  // fold repeat factor
        unsigned short ch = f2b(cc);
        chb[mi] = ch; clb[mi] = f2b(cc - b2f(ch));
        unsigned short bh = f2b(bv);
        bhb[mi] = bh; blb[mi] = f2b(bv - b2f(bh));
    }
    *reinterpret_cast<uint4*>(Chi + (size_t)row * KR + mh) = *reinterpret_cast<uint4*>(chb);
    *reinterpret_cast<uint4*>(Clo + (size_t)row * KR + mh) = *reinterpret_cast<uint4*>(clb);
    unsigned short* tb = TileB + (size_t)(h * 32 + jc) * TILE_B + (kg * 64 + c) * 8;
    *reinterpret_cast<uint4*>(tb)        = *reinterpret_cast<uint4*>(bhb);
    *reinterpret_cast<uint4*>(tb + 2048) = *reinterpret_cast<uint4*>(blb);
}

// ---------------------------------------------------------------------------
// K1b: V tiles (granule layout) via LDS transpose.  [validated R6-R13]
// ---------------------------------------------------------------------------
__global__ __launch_bounds__(256) void k_vtc(
    const float* __restrict__ v, unsigned short* __restrict__ TileV)
{
    __shared__ unsigned short sv[64 * 66];   // [j][d], stride 66
    const int tid = threadIdx.x;
    const int h = blockIdx.x >> 5, jc = blockIdx.x & 31;
    const float* src = v + (size_t)(h * LN + jc * 64) * 64;
    for (int i = tid; i < 4096; i += 256)
        sv[(i >> 6) * 66 + (i & 63)] = f2b(src[i]);
    __syncthreads();
    unsigned short* vt = TileV + (size_t)(h * 32 + jc) * TILE_V;
    #pragma unroll
    for (int it = 0; it < 2; ++it) {
        const int gi = tid + it * 256;               // 0..511
        const int jg = gi >> 6, d = gi & 63;
        unsigned short g8[8];
        #pragma unroll
        for (int jj = 0; jj < 8; ++jj)
            g8[jj] = sv[(jg * 8 + jj) * 66 + d];
        *reinterpret_cast<uint4*>(vt + (jg * 64 + d) * 8) = *reinterpret_cast<uint4*>(g8);
    }
}

// ---------------------------------------------------------------------------
// K2 (fused, single-S): 16-row blocks, 2048 total.
// Wave w owns col-subtile w (loop1) and d-slice w (PV); S in 128 VGPRs.
// B/V fragments read directly from global (L2-resident granule tiles).
// p_hat exchanged via half-width LDS (16 x 1024 bf16), filled per 16 chunks;
// P rows stored coalesced from that same buffer (wave w owns rows w*4+quad).
// All barriers are LDS-only (bar_lds): no vmcnt drains anywhere.
// b: [2:0]=xcd, [9:3]=tile(128), [10]=hbit; h=(b&7)*2+(b>>10).
// ---------------------------------------------------------------------------
#define PS_STRIDE 1032
__global__ __launch_bounds__(256, 2) void k_fuse(
    const unsigned short* __restrict__ Chi, const unsigned short* __restrict__ Clo,
    const unsigned short* __restrict__ TileB, const unsigned short* __restrict__ TileV,
    float* __restrict__ outO, float* __restrict__ outP)
{
    __shared__ unsigned short ps[16 * PS_STRIDE];   // 33KB: 16 rows x 1024 cols
    __shared__ float sRedM[4][16];
    __shared__ float sRedL[4][16];

    const int b = blockIdx.x;
    const int h = (b & 7) * 2 + (b >> 10);       // XCD-aware head mapping
    const int tile = (b >> 3) & 127;
    const int tid = threadIdx.x, w = tid >> 6, lane = tid & 63;
    const int quad = lane >> 4, n16 = lane & 15;
    const int rbase = tile * 16;
    const int hL = h * LN;

    const bf16x8 ahi = *reinterpret_cast<const bf16x8*>(Chi + (size_t)(hL + rbase + n16) * KR + quad * 8);
    const bf16x8 alo = *reinterpret_cast<const bf16x8*>(Clo + (size_t)(hL + rbase + n16) * KR + quad * 8);

    const unsigned short* bTile = TileB + (size_t)(h * 32) * TILE_B;
    const unsigned short* vTile = TileV + (size_t)(h * 32) * TILE_V;
    const int fragW = (quad * 64 + w * 16 + n16) * 8;   // B granule, shorts

    f32x4 zero = {0.f, 0.f, 0.f, 0.f};
    f32x4 sS[32];                                 // the S strip (128 VGPRs)

    // ---- loop 1: S -> registers, B-frags direct from global (no barriers) ----
    #pragma unroll
    for (int jc = 0; jc < 32; ++jc) {
        const unsigned short* g = bTile + jc * TILE_B;
        bf16x8 bhi = *reinterpret_cast<const bf16x8*>(g + fragW);
        bf16x8 blo = *reinterpret_cast<const bf16x8*>(g + 2048 + fragW);
        f32x4 acc = zero;
        acc = __builtin_amdgcn_mfma_f32_16x16x32_bf16(ahi, bhi, acc, 0, 0, 0);
        acc = __builtin_amdgcn_mfma_f32_16x16x32_bf16(ahi, blo, acc, 0, 0, 0);
        acc = __builtin_amdgcn_mfma_f32_16x16x32_bf16(alo, bhi, acc, 0, 0, 0);
        sS[jc] = acc;
    }

    // ---- stats in registers: m, then S -> p_hat with l accumulation ----
    float mr[4], li[4], liS;
    const int srow = w * 4 + quad;               // row this thread stores in P
    {
        float m0[4];
        #pragma unroll
        for (int r = 0; r < 4; ++r) {
            float mm = sS[0][r];
            #pragma unroll
            for (int jc = 1; jc < 32; ++jc) mm = fmaxf(mm, sS[jc][r]);
            #pragma unroll
            for (int off = 1; off <= 8; off <<= 1)
                mm = fmaxf(mm, __shfl_xor(mm, off, 64));
            m0[r] = mm;
        }
        if (n16 == 0) {
            #pragma unroll
            for (int r = 0; r < 4; ++r) sRedM[w][quad * 4 + r] = m0[r];
        }
        bar_lds();
        #pragma unroll
        for (int r = 0; r < 4; ++r)
            mr[r] = fmaxf(fmaxf(sRedM[0][quad*4+r], sRedM[1][quad*4+r]),
                          fmaxf(sRedM[2][quad*4+r], sRedM[3][quad*4+r]));
        float l0[4] = {0.f, 0.f, 0.f, 0.f};
        #pragma unroll
        for (int jc = 0; jc < 32; ++jc) {
            #pragma unroll
            for (int r = 0; r < 4; ++r) {
                float p = __expf(sS[jc][r] - mr[r]);  // <= 1, = 1 at the max
                sS[jc][r] = p;
                l0[r] += p;
            }
        }
        #pragma unroll
        for (int r = 0; r < 4; ++r) {
            float ll = l0[r];
            #pragma unroll
            for (int off = 1; off <= 8; off <<= 1)
                ll += __shfl_xor(ll, off, 64);
            l0[r] = ll;
        }
        if (n16 == 0) {
            #pragma unroll
            for (int r = 0; r < 4; ++r) sRedL[w][quad * 4 + r] = l0[r];
        }
        bar_lds();
        #pragma unroll
        for (int r = 0; r < 4; ++r)
            li[r] = 1.f / (sRedL[0][quad*4+r] + sRedL[1][quad*4+r]
                         + sRedL[2][quad*4+r] + sRedL[3][quad*4+r]);
        liS = 1.f / (sRedL[0][srow] + sRedL[1][srow]
                   + sRedL[2][srow] + sRedL[3][srow]);
    }

    // ---- loop 2: two 16-chunk halves; per half: fill ps, barrier, then
    //      barrier-free PV (V-frags direct from global) + coalesced P rows ----
    f32x4 o0 = zero, o1 = zero;
    float* prow = outP + (size_t)(hL + rbase + srow) * LN;
    #pragma unroll
    for (int half = 0; half < 2; ++half) {
        if (half) bar_lds();                 // ps reads of half 0 complete
        const int jc0 = half * 16;
        #pragma unroll
        for (int ji = 0; ji < 16; ++ji) {
            #pragma unroll
            for (int r = 0; r < 4; ++r)
                ps[(quad * 4 + r) * PS_STRIDE + ji * 64 + w * 16 + n16]
                    = f2b(sS[jc0 + ji][r]);
        }
        bar_lds();                           // ps visible to all waves

        // PV: V-frags direct from global, p_hat frags from ps
        #pragma unroll
        for (int ji = 0; ji < 16; ++ji) {
            const int jc = jc0 + ji;
            const unsigned short* vt = vTile + jc * TILE_V;
            bf16x8 pa0 = *reinterpret_cast<const bf16x8*>(
                ps + n16 * PS_STRIDE + ji * 64 + quad * 8);
            bf16x8 pa1 = *reinterpret_cast<const bf16x8*>(
                ps + n16 * PS_STRIDE + ji * 64 + 32 + quad * 8);
            bf16x8 vb0 = *reinterpret_cast<const bf16x8*>(
                vt + (quad * 64 + w * 16 + n16) * 8);
            bf16x8 vb1 = *reinterpret_cast<const bf16x8*>(
                vt + ((4 + quad) * 64 + w * 16 + n16) * 8);
            o0 = __builtin_amdgcn_mfma_f32_16x16x32_bf16(pa0, vb0, o0, 0, 0, 0);
            o1 = __builtin_amdgcn_mfma_f32_16x16x32_bf16(pa1, vb1, o1, 0, 0, 0);
        }

        // P stores: wave w streams rows w*4+quad, 1KB contiguous per instr
        #pragma unroll
        for (int ch = 0; ch < 16; ++ch) {
            const unsigned short* pp = ps + srow * PS_STRIDE + ch * 64 + n16 * 4;
            uint2 u = *reinterpret_cast<const uint2*>(pp);
            f32x4 pv;
            pv[0] = __uint_as_float((u.x & 0xffffu) << 16) * liS;
            pv[1] = __uint_as_float(u.x & 0xffff0000u) * liS;
            pv[2] = __uint_as_float((u.y & 0xffffu) << 16) * liS;
            pv[3] = __uint_as_float(u.y & 0xffff0000u) * liS;
            __builtin_nontemporal_store(pv, reinterpret_cast<f32x4*>(
                prow + half * 1024 + ch * 64 + n16 * 4));
        }
    }
    // O = (sum p_hat * V) * li
    #pragma unroll
    for (int r = 0; r < 4; ++r)
        __builtin_nontemporal_store((o0[r] + o1[r]) * li[r],
            &outO[(size_t)(hL + rbase + quad * 4 + r) * 64 + w * 16 + n16]);
}

// ---------------------------------------------------------------------------
extern "C" void kernel_launch(void* const* d_in, const int* in_sizes, int n_in,
                              void* d_out, int out_size, void* d_ws, size_t ws_size,
                              hipStream_t stream)
{
    (void)in_sizes; (void)n_in; (void)out_size; (void)ws_size;
    const float* q  = (const float*)d_in[0];
    const float* v  = (const float*)d_in[1];
    const float* Wa = (const float*)d_in[2];
    const float* ba = (const float*)d_in[3];
    const float* Wb = (const float*)d_in[4];
    const float* bb = (const float*)d_in[5];

    float* out = (float*)d_out;
    char* wsb = (char*)d_ws;
    const size_t MB = 1024 * 1024;
    unsigned short* Chi   = (unsigned short*)(wsb);            // 2MB
    unsigned short* Clo   = (unsigned short*)(wsb + 2 * MB);   // 2MB
    unsigned short* TileB = (unsigned short*)(wsb + 4 * MB);   // 4MB (512 x 8KB)
    unsigned short* TileV = (unsigned short*)(wsb + 8 * MB);   // 4MB (512 x 8KB)

    float* outO = out;                          // [H*L*64]
    float* outP = out + (size_t)HN * LN * 64;   // [H*L*L]

    hipLaunchKernelGGL(k_cb, dim3(512), dim3(256), 0, stream,
                       q, Wa, ba, Wb, bb, Chi, Clo, TileB);
    hipLaunchKernelGGL(k_vtc, dim3(512), dim3(256), 0, stream, v, TileV);
    hipLaunchKernelGGL(k_fuse, dim3(2048), dim3(256), 0, stream,
                       Chi, Clo, TileB, TileV, outO, outP);
}